// Round 5
// baseline (355.776 us; speedup 1.0000x reference)
//
#include <hip/hip_runtime.h>

#define BATCH  512
#define SEQLEN 256
#define EMB    128
#define HID    128

typedef _Float16 f16;
typedef __attribute__((ext_vector_type(8))) _Float16 half8;
typedef __attribute__((ext_vector_type(4))) _Float16 half4f;
typedef __attribute__((ext_vector_type(4))) float    floatx4;

#define L2E 1.44269504088896340736f
#define T2E 2.88539008177792681472f

__device__ __forceinline__ int swzB(int byte) {          // XOR swizzle, 16x256B tile
    return byte ^ (((byte >> 8) & 7) << 4);
}

struct XAcc { floatx4 z, r, h; };

// ---------------------------------------------------------------------------
// K0: prep — blocks 0..31: coalesced mask pack; blocks 32..255: item gather
// ---------------------------------------------------------------------------
__global__ void prep_kernel(const int* __restrict__ mask, const int* __restrict__ mid,
                            const float* __restrict__ emb,
                            unsigned* __restrict__ maskP, float* __restrict__ item_out) {
    const int bid = blockIdx.x, tid = threadIdx.x;
    if (bid < 32) {
        __shared__ int mls[16 * 256];
        for (int i = tid; i < 16 * 256; i += 256)
            mls[i] = mask[bid * 16 * 256 + i];
        __syncthreads();
        int t = tid;
        unsigned m = 0;
        #pragma unroll
        for (int r = 0; r < 16; ++r)
            m |= (unsigned)(mls[r * 256 + t] & 1) << r;
        maskP[bid * 256 + t] = m;
    } else {
        for (int i = (bid - 32) * 256 + tid; i < BATCH * EMB; i += 224 * 256) {
            int b = i >> 7, d = i & 127;
            item_out[i] = emb[(size_t)mid[b] * EMB + d];
        }
    }
}

// ---------------------------------------------------------------------------
// K1: fused gather + x-proj + GRU scan. 32 blocks x 512 thr (8 waves).
// x-projection for step t+1 precomputed during step t (XAcc double buffer) ->
// post-barrier chain is only 4 ha-MFMAs deep per gate. Scales folded into
// A-frags/biases. One barrier per step.
// ---------------------------------------------------------------------------
__global__ __launch_bounds__(512, 2) void gru_fused(
        const int* __restrict__ mid_hist, const float* __restrict__ emb,
        const float* __restrict__ W, const float* __restrict__ U,
        const float* __restrict__ bvec, const unsigned* __restrict__ maskP,
        float* __restrict__ out_user) {
    __shared__ __align__(16) f16 hpk[2][16 * 128];
    __shared__ __align__(16) f16 elds[4][16 * 128];

    const int tid   = threadIdx.x;
    const int lane  = tid & 63;
    const int w     = tid >> 6;        // 0..7
    const int l15   = lane & 15;
    const int g4    = lane >> 4;       // 0..3
    const int blk   = blockIdx.x;
    const int bbase = blk * 16;

    // --- A-frags with folded activation scales ------------------------------
    // p=0 (z), p=1 (r): rows scaled by -log2(e); p=2 (h): scaled by 2*log2(e)
    half8 uA[3][4], wA[3][4];
    #pragma unroll
    for (int p = 0; p < 3; ++p) {
        const float s = (p == 2) ? T2E : -L2E;
        #pragma unroll
        for (int kt = 0; kt < 4; ++kt) {
            half8 u, v;
            const int j = p * 128 + w * 16 + l15;
            #pragma unroll
            for (int e = 0; e < 8; ++e) {
                int k = kt * 32 + g4 * 8 + e;
                u[e] = (f16)(U[k * 384 + j] * s);
                v[e] = (f16)(W[k * 384 + j] * s);
            }
            uA[p][kt] = u; wA[p][kt] = v;
        }
    }

    // --- pre-scaled biases for this thread's 4 j's --------------------------
    const int jj = w * 16 + g4 * 4;
    float nbz[4], nbr[4], sxh[4], srh[4];
    {
        float4 a0 = *(const float4*)(bvec + jj);
        float4 a1 = *(const float4*)(bvec + 384 + jj);
        float4 c0 = *(const float4*)(bvec + 128 + jj);
        float4 c1 = *(const float4*)(bvec + 512 + jj);
        float4 d0 = *(const float4*)(bvec + 256 + jj);
        float4 d1 = *(const float4*)(bvec + 640 + jj);
        nbz[0] = -L2E*(a0.x+a1.x); nbz[1] = -L2E*(a0.y+a1.y);
        nbz[2] = -L2E*(a0.z+a1.z); nbz[3] = -L2E*(a0.w+a1.w);
        nbr[0] = -L2E*(c0.x+c1.x); nbr[1] = -L2E*(c0.y+c1.y);
        nbr[2] = -L2E*(c0.z+c1.z); nbr[3] = -L2E*(c0.w+c1.w);
        sxh[0] =  T2E*d0.x; sxh[1] = T2E*d0.y; sxh[2] = T2E*d0.z; sxh[3] = T2E*d0.w;
        srh[0] =  T2E*d1.x; srh[1] = T2E*d1.y; srh[2] = T2E*d1.z; srh[3] = T2E*d1.w;
    }

    // --- swizzled offsets (f16 elems) ---------------------------------------
    int aswz[4];
    #pragma unroll
    for (int kt = 0; kt < 4; ++kt)
        aswz[kt] = swzB(l15 * 256 + kt * 64 + g4 * 16) >> 1;
    const int hswz = swzB(l15 * 256 + jj * 2) >> 1;
    const int r_e  = tid >> 5;          // 0..15 staging row
    const int c32  = tid & 31;          // float4 chunk
    const int sswz = swzB(r_e * 256 + c32 * 8) >> 1;
    const int histbase = (bbase + r_e) * SEQLEN;
    const int mpbase   = blk * SEQLEN;

    for (int i = tid; i < 16 * 128; i += 512) hpk[0][i] = (f16)0.f;  // h0 = 0

    // --- prologue: stage emb(0),emb(1) into slots 0,1; rings ----------------
    {
        int i0 = mid_hist[histbase + 0];
        int i1 = mid_hist[histbase + 1];
        float4 v0 = *(const float4*)(emb + (size_t)i0 * EMB + c32 * 4);
        float4 v1 = *(const float4*)(emb + (size_t)i1 * EMB + c32 * 4);
        *(half4f*)&elds[0][sswz] = half4f{(f16)v0.x,(f16)v0.y,(f16)v0.z,(f16)v0.w};
        *(half4f*)&elds[1][sswz] = half4f{(f16)v1.x,(f16)v1.y,(f16)v1.z,(f16)v1.w};
    }
    int i2 = mid_hist[histbase + 2];
    int i3 = mid_hist[histbase + 3];
    float4   Ee = *(const float4*)(emb + (size_t)i2 * EMB + c32 * 4);  // emb(2)
    float4   Eo = *(const float4*)(emb + (size_t)i3 * EMB + c32 * 4);  // emb(3)
    int      Ie = mid_hist[histbase + 4];                              // idx(4)
    int      Io = mid_hist[histbase + 5];                              // idx(5)
    unsigned Me = maskP[mpbase + 0];                                   // msk(0)
    unsigned Mo = maskP[mpbase + 1];                                   // msk(1)

    float hreg[4] = {0.f, 0.f, 0.f, 0.f};
    __syncthreads();

    // --- prologue: x-acc for step 0 from slot 0 -----------------------------
    XAcc xA, xB;
    {
        half8 e0[4];
        #pragma unroll
        for (int kt = 0; kt < 4; ++kt) e0[kt] = *(const half8*)&elds[0][aswz[kt]];
        xA.z = floatx4{0,0,0,0}; xA.r = floatx4{0,0,0,0}; xA.h = floatx4{0,0,0,0};
        #pragma unroll
        for (int kt = 0; kt < 4; ++kt) {
            xA.z = __builtin_amdgcn_mfma_f32_16x16x32_f16(wA[0][kt], e0[kt], xA.z, 0,0,0);
            xA.r = __builtin_amdgcn_mfma_f32_16x16x32_f16(wA[1][kt], e0[kt], xA.r, 0,0,0);
            xA.h = __builtin_amdgcn_mfma_f32_16x16x32_f16(wA[2][kt], e0[kt], xA.h, 0,0,0);
        }
    }

    auto step = [&](int t, XAcc& xc, XAcc& xn, float4& E, int& I, unsigned& M) {
        const f16* hrd = hpk[t & 1];
        f16*       hwr = hpk[(t + 1) & 1];

        // ---- critical path: h frag reads -> depth-4 chains (C = x-acc) ----
        half8 ha[4];
        #pragma unroll
        for (int kt = 0; kt < 4; ++kt) ha[kt] = *(const half8*)&hrd[aswz[kt]];
        floatx4 arh = {0,0,0,0};
        #pragma unroll
        for (int kt = 0; kt < 4; ++kt) {
            xc.z = __builtin_amdgcn_mfma_f32_16x16x32_f16(uA[0][kt], ha[kt], xc.z, 0,0,0);
            xc.r = __builtin_amdgcn_mfma_f32_16x16x32_f16(uA[1][kt], ha[kt], xc.r, 0,0,0);
            arh  = __builtin_amdgcn_mfma_f32_16x16x32_f16(uA[2][kt], ha[kt], arh,  0,0,0);
        }

        // ---- off critical path: x-proj for step t+1 ----
        {
            const f16* erd = elds[(t + 1) & 3];
            half8 ea[4];
            #pragma unroll
            for (int kt = 0; kt < 4; ++kt) ea[kt] = *(const half8*)&erd[aswz[kt]];
            xn.z = floatx4{0,0,0,0}; xn.r = floatx4{0,0,0,0}; xn.h = floatx4{0,0,0,0};
            #pragma unroll
            for (int kt = 0; kt < 4; ++kt) {
                xn.z = __builtin_amdgcn_mfma_f32_16x16x32_f16(wA[0][kt], ea[kt], xn.z, 0,0,0);
                xn.r = __builtin_amdgcn_mfma_f32_16x16x32_f16(wA[1][kt], ea[kt], xn.r, 0,0,0);
                xn.h = __builtin_amdgcn_mfma_f32_16x16x32_f16(wA[2][kt], ea[kt], xn.h, 0,0,0);
            }
        }

        // ---- staging ring + prefetch reissue ----
        *(half4f*)&elds[(t + 2) & 3][sswz] =
            half4f{(f16)E.x, (f16)E.y, (f16)E.z, (f16)E.w};            // emb(t+2)
        int ii = I;
        E = *(const float4*)(emb + (size_t)ii * EMB + c32 * 4);        // emb(t+4)
        int t6 = t + 6 < SEQLEN ? t + 6 : SEQLEN - 1;
        I = mid_hist[histbase + t6];                                   // idx(t+6)
        unsigned mval = M;
        int tm = t + 2 < SEQLEN ? t + 2 : SEQLEN - 1;
        M = maskP[mpbase + tm];                                        // msk(t+2)

        // ---- gates + h update (b = l15, j = jj + r) ----
        const int mbit = (mval >> l15) & 1;
        #pragma unroll
        for (int r = 0; r < 4; ++r) {
            float z  = __builtin_amdgcn_rcpf(1.f + __builtin_amdgcn_exp2f(xc.z[r] + nbz[r]));
            float rg = __builtin_amdgcn_rcpf(1.f + __builtin_amdgcn_exp2f(xc.r[r] + nbr[r]));
            float u  = __builtin_fmaf(rg, arh[r] + srh[r], xc.h[r] + sxh[r]);
            float hh = __builtin_fmaf(-2.f, __builtin_amdgcn_rcpf(__builtin_amdgcn_exp2f(u) + 1.f), 1.f);
            float hn = __builtin_fmaf(z, hreg[r] - hh, hh);
            hreg[r]  = mbit ? hn : hreg[r];
        }
        *(half4f*)&hwr[hswz] = half4f{(f16)hreg[0], (f16)hreg[1], (f16)hreg[2], (f16)hreg[3]};

        __builtin_amdgcn_sched_barrier(0);
        asm volatile("s_waitcnt lgkmcnt(0)" ::: "memory");  // my LDS ops drained
        __builtin_amdgcn_s_barrier();                       // ONE barrier per step
        __builtin_amdgcn_sched_barrier(0);
    };

    #pragma unroll 1
    for (int t = 0; t < SEQLEN; t += 2) {
        step(t,     xA, xB, Ee, Ie, Me);
        step(t + 1, xB, xA, Eo, Io, Mo);
    }

    float4 o = { hreg[0], hreg[1], hreg[2], hreg[3] };
    *(float4*)(out_user + (size_t)(bbase + l15) * HID + jj) = o;
}

// ---------------------------------------------------------------------------
extern "C" void kernel_launch(void* const* d_in, const int* in_sizes, int n_in,
                              void* d_out, int out_size, void* d_ws, size_t ws_size,
                              hipStream_t stream) {
    const int*   mid      = (const int*)d_in[0];
    const int*   mid_hist = (const int*)d_in[1];
    const int*   mask     = (const int*)d_in[2];
    const float* emb      = (const float*)d_in[3];
    const float* W        = (const float*)d_in[4];
    const float* U        = (const float*)d_in[5];
    const float* bvec     = (const float*)d_in[6];

    float* user_out = (float*)d_out;                   // [512][128]
    float* item_out = (float*)d_out + BATCH * HID;     // [512][128]

    unsigned* maskP = (unsigned*)d_ws;                 // 32*256 u32

    prep_kernel<<<256, 256, 0, stream>>>(mask, mid, emb, maskP, item_out);
    gru_fused  <<<32, 512, 0, stream>>>(mid_hist, emb, W, U, bvec, maskP, user_out);
}